// Round 1
// 125.979 us; speedup vs baseline: 1.0186x; 1.0186x over previous
//
#include <hip/hip_runtime.h>
#include <hip/hip_bf16.h>

// NT-Xent loss: z1,z2 [4096,256] fp32 -> scalar loss.
// R4: GEMM k-loop de-latencied. R3's loop streamed B from global with a
// 1-step prefetch -> 8 serialized ~500cy latencies per block (MfmaUtil 8.9%).
// K=256 means a lane's whole B panel is 512B = 128 VGPRs, so:
//  - prefetch ALL B fragments (8 ksteps x 4) into registers BEFORE the one
//    __syncthreads(); its implicit vmcnt(0) drains A-staging + B in a single
//    latency event, overlapped with the co-resident block's compute;
//  - inner loop is now pure LDS-read + MFMA (no global ops);
//  - __launch_bounds__(256,2) pins VGPR<=256 so 2 blocks/CU is preserved;
//  - bijective XCD chunk swizzle (2080 = 8*260) for A-panel L2 locality.
// Triangle symmetry + fused exp/row/col sums + pair-dot in k_normalize kept.

#define TWO_N 8192
#define NPAIR 4096
#define DDIM  256
#define NT    64                    // 128-row tiles per dim
#define NBLK  (NT * (NT + 1) / 2)   // 2080 upper-triangle tiles
#define INV_T 2.0f

typedef __attribute__((ext_vector_type(8))) short bf16x8;
typedef __attribute__((ext_vector_type(4))) float f32x4;

typedef __attribute__((address_space(1))) void gvoid_t;
typedef __attribute__((address_space(3))) void lvoid_t;

__device__ __forceinline__ void gload_lds16(const void* g, void* l) {
    __builtin_amdgcn_global_load_lds((gvoid_t*)g, (lvoid_t*)l, 16, 0, 0);
}

// ---------------- Kernel 1: normalize + quantize + pair-dot + zero scratch --
// grid 1024 x 256: one wave per PAIR i (handles rows i and i+4096).
__global__ void k_normalize(const float* __restrict__ z1,
                            const float* __restrict__ z2,
                            __hip_bfloat16* __restrict__ zn,
                            float* __restrict__ e_diag,
                            float* __restrict__ pos,
                            float* __restrict__ row_sumexp,
                            float* __restrict__ out) {
    if (threadIdx.x < 8) row_sumexp[blockIdx.x * 8 + threadIdx.x] = 0.0f;
    if (blockIdx.x == 0 && threadIdx.x == 0) out[0] = 0.0f;

    const int w    = threadIdx.x >> 6;
    const int lane = threadIdx.x & 63;
    const int i    = blockIdx.x * 4 + w;

    float4 a = ((const float4*)(z1 + (size_t)i * DDIM))[lane];
    float4 b = ((const float4*)(z2 + (size_t)i * DDIM))[lane];

    float s1 = a.x * a.x + a.y * a.y + a.z * a.z + a.w * a.w;
    float s2 = b.x * b.x + b.y * b.y + b.z * b.z + b.w * b.w;
    float dd = a.x * b.x + a.y * b.y + a.z * b.z + a.w * b.w;
#pragma unroll
    for (int m = 1; m < 64; m <<= 1) {
        s1 += __shfl_xor(s1, m, 64);
        s2 += __shfl_xor(s2, m, 64);
        dd += __shfl_xor(dd, m, 64);
    }

    float inv1 = 1.0f / fmaxf(sqrtf(s1), 1e-8f);   // matches reference eps
    float inv2 = 1.0f / fmaxf(sqrtf(s2), 1e-8f);

    __hip_bfloat16 q1[4], q2[4];
    q1[0] = __float2bfloat16(a.x * inv1); q1[1] = __float2bfloat16(a.y * inv1);
    q1[2] = __float2bfloat16(a.z * inv1); q1[3] = __float2bfloat16(a.w * inv1);
    q2[0] = __float2bfloat16(b.x * inv2); q2[1] = __float2bfloat16(b.y * inv2);
    q2[2] = __float2bfloat16(b.z * inv2); q2[3] = __float2bfloat16(b.w * inv2);

    float qs1 = 0.0f, qs2 = 0.0f;
#pragma unroll
    for (int j = 0; j < 4; ++j) {
        float f1 = __bfloat162float(q1[j]);
        float f2 = __bfloat162float(q2[j]);
        qs1 += f1 * f1;
        qs2 += f2 * f2;
    }
#pragma unroll
    for (int m = 1; m < 64; m <<= 1) {
        qs1 += __shfl_xor(qs1, m, 64);
        qs2 += __shfl_xor(qs2, m, 64);
    }

    *reinterpret_cast<uint2*>(zn + (size_t)i * DDIM + lane * 4) =
        *reinterpret_cast<uint2*>(q1);
    *reinterpret_cast<uint2*>(zn + (size_t)(i + NPAIR) * DDIM + lane * 4) =
        *reinterpret_cast<uint2*>(q2);

    if (lane == 0) {
        e_diag[i]         = __expf(qs1 * INV_T);   // matches GEMM's bf16 self-dot
        e_diag[i + NPAIR] = __expf(qs2 * INV_T);
        pos[i]            = dd * inv1 * inv2 * INV_T;  // positive-pair term, pure fp32
    }
}

// ---------------- Kernel 2: symmetric MFMA self-GEMM + exp + row/col sums ----
// 2080 blocks (upper-triangle 128x128 tiles), 256 threads (2x2 waves of 64x64).
// A-tile full K in LDS (swizzled: row r, 16B-chunk slot c' holds global chunk
// ck with ck = (c'&24) | ((c'&7)^(r&7))), staged with global_load_lds(16B).
// B panel fully prefetched into registers (8 ksteps x 4 frags x 16B / lane).
__global__ __launch_bounds__(256, 2)
void k_gemm_sumexp(const __hip_bfloat16* __restrict__ zn,
                   float* __restrict__ row_sumexp) {
    __shared__ __align__(128) __hip_bfloat16 Asmem[128 * DDIM];   // 64 KB

    const int tid  = threadIdx.x;
    const int lane = tid & 63;
    const int w    = tid >> 6;
    const int wr   = w >> 1;          // wave row-half (0/1)
    const int wc   = w & 1;           // wave col-half (0/1)
    const int lr   = lane & 15;
    const int quad = lane >> 4;

    // --- XCD chunk swizzle: 2080 = 8*260 exactly, bijective. Blocks with the
    //     same blockIdx%8 land on the same XCD and walk a contiguous logical
    //     chunk (shared rt row-panels -> A stays hot in that XCD's L2). ---
    int b = (blockIdx.x & 7) * (NBLK / 8) + (blockIdx.x >> 3);

    // --- triangular decode: block b -> (rt, ct), rt <= ct (verified R2) ---
    int rt = (int)(64.5f - sqrtf(64.5f * 64.5f - 2.0f * (float)b));
    if (rt < 0) rt = 0;
    if (rt > NT - 1) rt = NT - 1;
    while (rt > 0 && NT * rt - (rt * (rt - 1)) / 2 > b) --rt;
    while (NT * (rt + 1) - ((rt + 1) * rt) / 2 <= b) ++rt;
    const int ct   = rt + (b - (NT * rt - (rt * (rt - 1)) / 2));
    const bool diag = (rt == ct);

    const int row_base = rt * 128;
    const int col_base = ct * 128;

    // --- B fragment global pointers: row = col_base + wc*64 + ni*16 + lr ---
    const __hip_bfloat16* gB[4];
#pragma unroll
    for (int ni = 0; ni < 4; ++ni)
        gB[ni] = zn + (size_t)(col_base + wc * 64 + ni * 16 + lr) * DDIM + quad * 8;

    // --- issue the FULL B panel into registers: 32 x 16B per lane.
    //     All in flight together with the A staging below; the single
    //     barrier's vmcnt(0) drains everything at once. ---
    bf16x8 Bfr[8][4];
#pragma unroll
    for (int ks = 0; ks < 8; ++ks)
#pragma unroll
        for (int ni = 0; ni < 4; ++ni)
            Bfr[ks][ni] = *(const bf16x8*)(gB[ni] + ks * 32);

    // --- stage A tile: slot s = j*256+tid -> row = j*8 + (tid>>5), c' = tid&31;
    //     source chunk ck is per-thread constant. 16 rounds of 16B/lane. ---
    {
        const int ck = (tid & 24) | ((tid & 7) ^ (tid >> 5));
        const char* gA = (const char*)(zn + (size_t)row_base * DDIM)
                       + (tid >> 5) * (DDIM * 2) + ck * 16;
        char* lA = (char*)Asmem + tid * 16;
#pragma unroll
        for (int j = 0; j < 16; ++j)
            gload_lds16(gA + (size_t)j * 8 * (DDIM * 2), lA + j * 4096);
    }
    __syncthreads();   // the ONLY barrier (drains A staging + B prefetch)

    // --- A fragment LDS byte offsets (swizzled) ---
    // A(mi,kstep): row = wr*64+mi*16+lr, byte = row*512 + (kstep>>1)*128
    //              + [ (quad ^ (lr&7)) ^ ((kstep&1)<<2) ] * 16
    int pa[4];
#pragma unroll
    for (int mi = 0; mi < 4; ++mi)
        pa[mi] = (wr * 64 + mi * 16 + lr) * (DDIM * 2) + ((quad ^ (lr & 7)) << 4);

    f32x4 acc[4][4];
#pragma unroll
    for (int mi = 0; mi < 4; ++mi)
#pragma unroll
        for (int ni = 0; ni < 4; ++ni) acc[mi][ni] = (f32x4){0.f, 0.f, 0.f, 0.f};

    bf16x8 afc[4];
#pragma unroll
    for (int mi = 0; mi < 4; ++mi)
        afc[mi] = *(const bf16x8*)((const char*)Asmem + pa[mi]);

#pragma unroll
    for (int kstep = 0; kstep < 8; ++kstep) {
        bf16x8 afn[4];
        if (kstep < 7) {
            const int kn   = kstep + 1;
            const int koff = ((kn >> 1) << 7);
            const int kx   = ((kn & 1) << 6);
#pragma unroll
            for (int mi = 0; mi < 4; ++mi)
                afn[mi] = *(const bf16x8*)((const char*)Asmem + ((pa[mi] ^ kx) + koff));
        }
#pragma unroll
        for (int mi = 0; mi < 4; ++mi)
#pragma unroll
            for (int ni = 0; ni < 4; ++ni)
                acc[mi][ni] = __builtin_amdgcn_mfma_f32_16x16x32_bf16(
                    afc[mi], Bfr[kstep][ni], acc[mi][ni], 0, 0, 0);
        if (kstep < 7) {
#pragma unroll
            for (int mi = 0; mi < 4; ++mi) afc[mi] = afn[mi];
        }
    }

    // --- epilogue: e = exp(2*dot); row-sums always, col-sums if off-diag ---
    // C/D layout (verified R1/R2): col = lane&15, row = quad*4 + reg.
    float rs[4][4];
    float cs[4];
#pragma unroll
    for (int mi = 0; mi < 4; ++mi)
#pragma unroll
        for (int r = 0; r < 4; ++r) rs[mi][r] = 0.0f;
#pragma unroll
    for (int ni = 0; ni < 4; ++ni) cs[ni] = 0.0f;

#pragma unroll
    for (int mi = 0; mi < 4; ++mi)
#pragma unroll
        for (int ni = 0; ni < 4; ++ni)
#pragma unroll
            for (int r = 0; r < 4; ++r) {
                float e = __expf(acc[mi][ni][r] * INV_T);
                rs[mi][r] += e;
                cs[ni] += e;
            }

    // row sums: reduce over lane bits 0..3 (the 16 columns)
#pragma unroll
    for (int mi = 0; mi < 4; ++mi) {
#pragma unroll
        for (int r = 0; r < 4; ++r) {
            float v = rs[mi][r];
            v += __shfl_xor(v, 1, 64);
            v += __shfl_xor(v, 2, 64);
            v += __shfl_xor(v, 4, 64);
            v += __shfl_xor(v, 8, 64);
            if (lr == 0) {
                int row = row_base + wr * 64 + mi * 16 + quad * 4 + r;
                atomicAdd(&row_sumexp[row], v);
            }
        }
    }

    // col sums: reduce over lane bits 4..5
    if (!diag) {
#pragma unroll
        for (int ni = 0; ni < 4; ++ni) {
            float v = cs[ni];
            v += __shfl_xor(v, 16, 64);
            v += __shfl_xor(v, 32, 64);
            if (quad == 0) {
                int col = col_base + wc * 64 + ni * 16 + lr;
                atomicAdd(&row_sumexp[col], v);
            }
        }
    }
}

// ---------------- Kernel 3: tiny finisher ----------------
// grid 16 x 256: one thread per pair index.
__global__ void k_final(const float* __restrict__ row_sumexp,
                        const float* __restrict__ e_diag,
                        const float* __restrict__ pos,
                        float* __restrict__ out) {
    const int i    = blockIdx.x * 256 + threadIdx.x;   // 0..4095
    const int w    = threadIdx.x >> 6;
    const int lane = threadIdx.x & 63;

    float t = logf(row_sumexp[i] - e_diag[i])
            + logf(row_sumexp[i + NPAIR] - e_diag[i + NPAIR])
            - 2.0f * pos[i];
#pragma unroll
    for (int m = 1; m < 64; m <<= 1) t += __shfl_xor(t, m, 64);

    __shared__ float ps[4];
    if (lane == 0) ps[w] = t;
    __syncthreads();
    if (threadIdx.x == 0) {
        float s = (ps[0] + ps[1] + ps[2] + ps[3]) * (1.0f / (float)TWO_N);
        atomicAdd(out, s);
    }
}

extern "C" void kernel_launch(void* const* d_in, const int* in_sizes, int n_in,
                              void* d_out, int out_size, void* d_ws, size_t ws_size,
                              hipStream_t stream) {
    const float* z1 = (const float*)d_in[0];
    const float* z2 = (const float*)d_in[1];
    float* out = (float*)d_out;

    char* ws = (char*)d_ws;
    __hip_bfloat16* zn  = (__hip_bfloat16*)ws;                       // 4 MB
    float* row_sumexp   = (float*)(ws + (size_t)TWO_N * DDIM * 2);   // 32 KB
    float* e_diag       = row_sumexp + TWO_N;                        // 32 KB
    float* pos          = e_diag + TWO_N;                            // 16 KB

    k_normalize<<<NPAIR / 4, 256, 0, stream>>>(z1, z2, zn, e_diag, pos,
                                               row_sumexp, out);
    k_gemm_sumexp<<<NBLK, 256, 0, stream>>>(zn, row_sumexp);
    k_final<<<NPAIR / 256, 256, 0, stream>>>(row_sumexp, e_diag, pos, out);
}

// Round 2
// 125.632 us; speedup vs baseline: 1.0214x; 1.0028x over previous
//
#include <hip/hip_runtime.h>
#include <hip/hip_bf16.h>

// NT-Xent loss: z1,z2 [4096,256] fp32 -> scalar loss.
// R5: R4's full-B register prefetch was DEFEATED by the compiler (VGPR=112
// proves the 128-VGPR B panel was not resident; loads were sunk back into the
// k-loop -> 8 serialized L2 latencies/block, MfmaUtil stuck at 10%).
// Fix: pin every B fragment with asm volatile("" : "+v"(frag)) after issue,
// BEFORE the single __syncthreads. "+v" makes the loaded value an asm output
// the compiler cannot rematerialize or sink. A-staging (global_load_lds) is
// issued first so the one vmcnt drain at the pin covers A too (vmcnt is
// in-order). Inner loop is then pure LDS-read + MFMA.
// Kept from R3/R4: triangle symmetry, fused exp/row/col sums, XOR-swizzled
// A tile, bijective XCD chunk swizzle, pair-dot folded into k_normalize.

#define TWO_N 8192
#define NPAIR 4096
#define DDIM  256
#define NT    64                    // 128-row tiles per dim
#define NBLK  (NT * (NT + 1) / 2)   // 2080 upper-triangle tiles
#define INV_T 2.0f

typedef __attribute__((ext_vector_type(8))) short bf16x8;
typedef __attribute__((ext_vector_type(4))) float f32x4;

typedef __attribute__((address_space(1))) void gvoid_t;
typedef __attribute__((address_space(3))) void lvoid_t;

__device__ __forceinline__ void gload_lds16(const void* g, void* l) {
    __builtin_amdgcn_global_load_lds((gvoid_t*)g, (lvoid_t*)l, 16, 0, 0);
}

// ---------------- Kernel 1: normalize + quantize + pair-dot + zero scratch --
// grid 1024 x 256: one wave per PAIR i (handles rows i and i+4096).
__global__ void k_normalize(const float* __restrict__ z1,
                            const float* __restrict__ z2,
                            __hip_bfloat16* __restrict__ zn,
                            float* __restrict__ e_diag,
                            float* __restrict__ pos,
                            float* __restrict__ row_sumexp,
                            float* __restrict__ out) {
    if (threadIdx.x < 8) row_sumexp[blockIdx.x * 8 + threadIdx.x] = 0.0f;
    if (blockIdx.x == 0 && threadIdx.x == 0) out[0] = 0.0f;

    const int w    = threadIdx.x >> 6;
    const int lane = threadIdx.x & 63;
    const int i    = blockIdx.x * 4 + w;

    float4 a = ((const float4*)(z1 + (size_t)i * DDIM))[lane];
    float4 b = ((const float4*)(z2 + (size_t)i * DDIM))[lane];

    float s1 = a.x * a.x + a.y * a.y + a.z * a.z + a.w * a.w;
    float s2 = b.x * b.x + b.y * b.y + b.z * b.z + b.w * b.w;
    float dd = a.x * b.x + a.y * b.y + a.z * b.z + a.w * b.w;
#pragma unroll
    for (int m = 1; m < 64; m <<= 1) {
        s1 += __shfl_xor(s1, m, 64);
        s2 += __shfl_xor(s2, m, 64);
        dd += __shfl_xor(dd, m, 64);
    }

    float inv1 = 1.0f / fmaxf(sqrtf(s1), 1e-8f);   // matches reference eps
    float inv2 = 1.0f / fmaxf(sqrtf(s2), 1e-8f);

    __hip_bfloat16 q1[4], q2[4];
    q1[0] = __float2bfloat16(a.x * inv1); q1[1] = __float2bfloat16(a.y * inv1);
    q1[2] = __float2bfloat16(a.z * inv1); q1[3] = __float2bfloat16(a.w * inv1);
    q2[0] = __float2bfloat16(b.x * inv2); q2[1] = __float2bfloat16(b.y * inv2);
    q2[2] = __float2bfloat16(b.z * inv2); q2[3] = __float2bfloat16(b.w * inv2);

    float qs1 = 0.0f, qs2 = 0.0f;
#pragma unroll
    for (int j = 0; j < 4; ++j) {
        float f1 = __bfloat162float(q1[j]);
        float f2 = __bfloat162float(q2[j]);
        qs1 += f1 * f1;
        qs2 += f2 * f2;
    }
#pragma unroll
    for (int m = 1; m < 64; m <<= 1) {
        qs1 += __shfl_xor(qs1, m, 64);
        qs2 += __shfl_xor(qs2, m, 64);
    }

    *reinterpret_cast<uint2*>(zn + (size_t)i * DDIM + lane * 4) =
        *reinterpret_cast<uint2*>(q1);
    *reinterpret_cast<uint2*>(zn + (size_t)(i + NPAIR) * DDIM + lane * 4) =
        *reinterpret_cast<uint2*>(q2);

    if (lane == 0) {
        e_diag[i]         = __expf(qs1 * INV_T);   // matches GEMM's bf16 self-dot
        e_diag[i + NPAIR] = __expf(qs2 * INV_T);
        pos[i]            = dd * inv1 * inv2 * INV_T;  // positive-pair term, pure fp32
    }
}

// ---------------- Kernel 2: symmetric MFMA self-GEMM + exp + row/col sums ----
// 2080 blocks (upper-triangle 128x128 tiles), 256 threads (2x2 waves of 64x64).
// A-tile full K in LDS (swizzled), staged with global_load_lds(16B).
// B panel fully prefetched into registers and PINNED there with asm "+v".
__global__ __launch_bounds__(256, 2)
void k_gemm_sumexp(const __hip_bfloat16* __restrict__ zn,
                   float* __restrict__ row_sumexp) {
    __shared__ __align__(128) __hip_bfloat16 Asmem[128 * DDIM];   // 64 KB

    const int tid  = threadIdx.x;
    const int lane = tid & 63;
    const int w    = tid >> 6;
    const int wr   = w >> 1;          // wave row-half (0/1)
    const int wc   = w & 1;           // wave col-half (0/1)
    const int lr   = lane & 15;
    const int quad = lane >> 4;

    // --- XCD chunk swizzle: 2080 = 8*260 exactly, bijective. ---
    int b = (blockIdx.x & 7) * (NBLK / 8) + (blockIdx.x >> 3);

    // --- triangular decode: block b -> (rt, ct), rt <= ct (verified R2) ---
    int rt = (int)(64.5f - sqrtf(64.5f * 64.5f - 2.0f * (float)b));
    if (rt < 0) rt = 0;
    if (rt > NT - 1) rt = NT - 1;
    while (rt > 0 && NT * rt - (rt * (rt - 1)) / 2 > b) --rt;
    while (NT * (rt + 1) - ((rt + 1) * rt) / 2 <= b) ++rt;
    const int ct   = rt + (b - (NT * rt - (rt * (rt - 1)) / 2));
    const bool diag = (rt == ct);

    const int row_base = rt * 128;
    const int col_base = ct * 128;

    // --- stage A tile FIRST: slot s = j*256+tid -> row = j*8 + (tid>>5),
    //     c' = tid&31; source chunk ck per-thread constant. 16 x 16B/lane. ---
    {
        const int ck = (tid & 24) | ((tid & 7) ^ (tid >> 5));
        const char* gA = (const char*)(zn + (size_t)row_base * DDIM)
                       + (tid >> 5) * (DDIM * 2) + ck * 16;
        char* lA = (char*)Asmem + tid * 16;
#pragma unroll
        for (int j = 0; j < 16; ++j)
            gload_lds16(gA + (size_t)j * 8 * (DDIM * 2), lA + j * 4096);
    }

    // --- B fragment global pointers: row = col_base + wc*64 + ni*16 + lr ---
    const __hip_bfloat16* gB[4];
#pragma unroll
    for (int ni = 0; ni < 4; ++ni)
        gB[ni] = zn + (size_t)(col_base + wc * 64 + ni * 16 + lr) * DDIM + quad * 8;

    // --- issue the FULL B panel into registers: 32 x 16B per lane ---
    bf16x8 Bfr[8][4];
#pragma unroll
    for (int ks = 0; ks < 8; ++ks)
#pragma unroll
        for (int ni = 0; ni < 4; ++ni)
            Bfr[ks][ni] = *(const bf16x8*)(gB[ni] + ks * 32);

    // --- PIN the B panel in registers (R5 fix). "+v" makes each fragment an
    //     asm output: the compiler must complete the load here and cannot
    //     sink/rematerialize it into the k-loop. Forces one vmcnt drain that
    //     (in-order) also covers the A staging above. ---
#pragma unroll
    for (int ks = 0; ks < 8; ++ks)
#pragma unroll
        for (int ni = 0; ni < 4; ++ni)
            asm volatile("" : "+v"(Bfr[ks][ni]));

    __syncthreads();   // the ONLY barrier (A staging already drained)

    // --- A fragment LDS byte offsets (swizzled) ---
    // A(mi,kstep): row = wr*64+mi*16+lr, byte = row*512 + (kstep>>1)*128
    //              + [ (quad ^ (lr&7)) ^ ((kstep&1)<<2) ] * 16
    int pa[4];
#pragma unroll
    for (int mi = 0; mi < 4; ++mi)
        pa[mi] = (wr * 64 + mi * 16 + lr) * (DDIM * 2) + ((quad ^ (lr & 7)) << 4);

    f32x4 acc[4][4];
#pragma unroll
    for (int mi = 0; mi < 4; ++mi)
#pragma unroll
        for (int ni = 0; ni < 4; ++ni) acc[mi][ni] = (f32x4){0.f, 0.f, 0.f, 0.f};

    bf16x8 afc[4];
#pragma unroll
    for (int mi = 0; mi < 4; ++mi)
        afc[mi] = *(const bf16x8*)((const char*)Asmem + pa[mi]);

#pragma unroll
    for (int kstep = 0; kstep < 8; ++kstep) {
        bf16x8 afn[4];
        if (kstep < 7) {
            const int kn   = kstep + 1;
            const int koff = ((kn >> 1) << 7);
            const int kx   = ((kn & 1) << 6);
#pragma unroll
            for (int mi = 0; mi < 4; ++mi)
                afn[mi] = *(const bf16x8*)((const char*)Asmem + ((pa[mi] ^ kx) + koff));
        }
#pragma unroll
        for (int mi = 0; mi < 4; ++mi)
#pragma unroll
            for (int ni = 0; ni < 4; ++ni)
                acc[mi][ni] = __builtin_amdgcn_mfma_f32_16x16x32_bf16(
                    afc[mi], Bfr[kstep][ni], acc[mi][ni], 0, 0, 0);
        if (kstep < 7) {
#pragma unroll
            for (int mi = 0; mi < 4; ++mi) afc[mi] = afn[mi];
        }
    }

    // --- epilogue: e = exp(2*dot); row-sums always, col-sums if off-diag ---
    // C/D layout (verified R1/R2): col = lane&15, row = quad*4 + reg.
    float rs[4][4];
    float cs[4];
#pragma unroll
    for (int mi = 0; mi < 4; ++mi)
#pragma unroll
        for (int r = 0; r < 4; ++r) rs[mi][r] = 0.0f;
#pragma unroll
    for (int ni = 0; ni < 4; ++ni) cs[ni] = 0.0f;

#pragma unroll
    for (int mi = 0; mi < 4; ++mi)
#pragma unroll
        for (int ni = 0; ni < 4; ++ni)
#pragma unroll
            for (int r = 0; r < 4; ++r) {
                float e = __expf(acc[mi][ni][r] * INV_T);
                rs[mi][r] += e;
                cs[ni] += e;
            }

    // row sums: reduce over lane bits 0..3 (the 16 columns)
#pragma unroll
    for (int mi = 0; mi < 4; ++mi) {
#pragma unroll
        for (int r = 0; r < 4; ++r) {
            float v = rs[mi][r];
            v += __shfl_xor(v, 1, 64);
            v += __shfl_xor(v, 2, 64);
            v += __shfl_xor(v, 4, 64);
            v += __shfl_xor(v, 8, 64);
            if (lr == 0) {
                int row = row_base + wr * 64 + mi * 16 + quad * 4 + r;
                atomicAdd(&row_sumexp[row], v);
            }
        }
    }

    // col sums: reduce over lane bits 4..5
    if (!diag) {
#pragma unroll
        for (int ni = 0; ni < 4; ++ni) {
            float v = cs[ni];
            v += __shfl_xor(v, 16, 64);
            v += __shfl_xor(v, 32, 64);
            if (quad == 0) {
                int col = col_base + wc * 64 + ni * 16 + lr;
                atomicAdd(&row_sumexp[col], v);
            }
        }
    }
}

// ---------------- Kernel 3: tiny finisher ----------------
// grid 16 x 256: one thread per pair index.
__global__ void k_final(const float* __restrict__ row_sumexp,
                        const float* __restrict__ e_diag,
                        const float* __restrict__ pos,
                        float* __restrict__ out) {
    const int i    = blockIdx.x * 256 + threadIdx.x;   // 0..4095
    const int w    = threadIdx.x >> 6;
    const int lane = threadIdx.x & 63;

    float t = logf(row_sumexp[i] - e_diag[i])
            + logf(row_sumexp[i + NPAIR] - e_diag[i + NPAIR])
            - 2.0f * pos[i];
#pragma unroll
    for (int m = 1; m < 64; m <<= 1) t += __shfl_xor(t, m, 64);

    __shared__ float ps[4];
    if (lane == 0) ps[w] = t;
    __syncthreads();
    if (threadIdx.x == 0) {
        float s = (ps[0] + ps[1] + ps[2] + ps[3]) * (1.0f / (float)TWO_N);
        atomicAdd(out, s);
    }
}

extern "C" void kernel_launch(void* const* d_in, const int* in_sizes, int n_in,
                              void* d_out, int out_size, void* d_ws, size_t ws_size,
                              hipStream_t stream) {
    const float* z1 = (const float*)d_in[0];
    const float* z2 = (const float*)d_in[1];
    float* out = (float*)d_out;

    char* ws = (char*)d_ws;
    __hip_bfloat16* zn  = (__hip_bfloat16*)ws;                       // 4 MB
    float* row_sumexp   = (float*)(ws + (size_t)TWO_N * DDIM * 2);   // 32 KB
    float* e_diag       = row_sumexp + TWO_N;                        // 32 KB
    float* pos          = e_diag + TWO_N;                            // 16 KB

    k_normalize<<<NPAIR / 4, 256, 0, stream>>>(z1, z2, zn, e_diag, pos,
                                               row_sumexp, out);
    k_gemm_sumexp<<<NBLK, 256, 0, stream>>>(zn, row_sumexp);
    k_final<<<NPAIR / 256, 256, 0, stream>>>(row_sumexp, e_diag, pos, out);
}